// Round 13
// baseline (5505.633 us; speedup 1.0000x reference)
//
#include <hip/hip_runtime.h>

#define VOCABN 401
#define EN 256
#define HN 768
#define H3N 2304
#define ON 3
#define BN 64
#define TN 1024

// 16 replicas x 16 WGs; WG = 768 threads = 12 waves.
// MFMA: wave = (wr in 3 row-groups x wk in 4 k-quarters); rows 144 = 9 tiles of 16.
// Pollers: tid<384. Gate threads: tid in [576,768) own (b, jl).
#define NREP 16
#define WGPR 16
#define BPR  4
#define JPW  48
#define NTH  768

typedef _Float16 f16x8 __attribute__((ext_vector_type(8)));
typedef float f32x4 __attribute__((ext_vector_type(4)));
typedef unsigned long long u64;

// workgroup barrier draining ONLY lgkm — in-flight global poll loads survive.
__device__ __forceinline__ void barrier_lgkm() {
    asm volatile("s_waitcnt lgkmcnt(0)\n\ts_barrier" ::: "memory");
}

// ---------------- K1: gtab[v][g] = dot(embed[v], W_ih[g]) + b_ih[g]  (w-stationary)
__global__ __launch_bounds__(256)
void k_build_gtab(const float* __restrict__ embed, const float* __restrict__ wih,
                  const float* __restrict__ bih, float* __restrict__ gtab) {
    const int g  = blockIdx.x * 64 + (threadIdx.x >> 2);
    const int ql = threadIdx.x & 3;
    const int v0 = blockIdx.y * 26;
    const int v1 = min(VOCABN, v0 + 26);
    float4 w[16];
    const float4* s4 = (const float4*)(wih + (size_t)g * EN + ql * 64);
#pragma unroll
    for (int i = 0; i < 16; ++i) w[i] = s4[i];
    const float bias = bih[g];
    for (int v = v0; v < v1; ++v) {
        const float4* e4 = (const float4*)(embed + (size_t)v * EN + ql * 64);
        float acc = 0.f;
#pragma unroll
        for (int i = 0; i < 16; ++i) {
            float4 e = e4[i];
            acc += w[i].x * e.x + w[i].y * e.y + w[i].z * e.z + w[i].w * e.w;
        }
        acc += __shfl_xor(acc, 1, 64);
        acc += __shfl_xor(acc, 2, 64);
        if (ql == 0) gtab[(size_t)v * H3N + g] = acc + bias;
    }
}

// ---------------- K2: persistent-weight recurrence; batch-staggered pipeline,
// MFMA dot engine, depth-1 poll ring, lgkm-only barriers.
// h word (u32): [31:16]=step tag, [15:0]=f16 bits; u64 = j-pair. memset-0 == t=0.
// Stage (t,b): [pollers: verify vin, deposit tile b, issue poll(b+1)] | bar |
// [all 12 waves: 6x ds_read_b128 B-broadcast + 18 MFMA + psum writes] | bar |
// [gate threads of batch b: reduce 4 k-partials, gates, paired tagged store].
// Anti-overwrite induction as r9-r12. Agent-scope relaxed atomics only.
__global__ __launch_bounds__(NTH, 1)
void k_rnn(const int* __restrict__ tokens, const float* __restrict__ whh,
           const float* __restrict__ gtab, const float* __restrict__ bhh,
           unsigned* __restrict__ hbuf, float* __restrict__ hout) {
    const int R    = blockIdx.x & (NREP - 1);
    const int wg   = blockIdx.x >> 4;
    const int tid  = threadIdx.x;
    const int lane = tid & 63;
    const int wave = tid >> 6;                 // 0..11
    const int wr   = wave % 3;                 // row-group: rows [48*wr, 48*wr+48)
    const int wk   = wave / 3;                 // k-quarter: k in [192*wk, 192*wk+192)
    const int koff8 = ((lane >> 4) & 3) * 8;   // k-sub-offset within a 32-k step
    const int kbase = wk * 192;

    __shared__ __align__(16) _Float16 hT[BPR * HN];   // [b][768] linear, 6144 B
    __shared__ __align__(16) float psum[4][144];      // k-quarter partial sums, 2304 B

    // ---- one-time: A fragments (weights) -> 18 statically-indexed f16x8 (72 VGPRs)
    // A layout (m89/m97-consistent): lane holds row = tile_base + (lane&15),
    // k = kstep*32 + ((lane>>4)&3)*8 + i.
    f16x8 a[3][6];
#pragma unroll
    for (int tt = 0; tt < 3; ++tt) {
        const int lr  = wr * 48 + tt * 16 + (lane & 15);   // local row 0..143
        const int g   = lr / 48;                           // gate: 0=r 1=z 2=n
        const int jlr = lr % 48;
        const float* wsrc = whh + (size_t)(g * HN + wg * JPW + jlr) * HN;
#pragma unroll
        for (int ks = 0; ks < 6; ++ks) {
            const float4* p4 = (const float4*)(wsrc + kbase + ks * 32 + koff8);
            float4 x0 = p4[0], x1 = p4[1];
            f16x8 t;
            t[0] = (_Float16)x0.x; t[1] = (_Float16)x0.y;
            t[2] = (_Float16)x0.z; t[3] = (_Float16)x0.w;
            t[4] = (_Float16)x1.x; t[5] = (_Float16)x1.y;
            t[6] = (_Float16)x1.z; t[7] = (_Float16)x1.w;
            a[tt][ks] = t;
        }
    }

    u64* hb2 = (u64*)hbuf + (size_t)R * (2 * BPR * 384);

    // gate-thread persistent state (tid in [576,768)): owns (bown, jlown)
    const int gt    = tid - 576;
    const int bown  = (gt >= 0) ? gt / 48 : 0;
    const int jlown = (gt >= 0) ? gt - bown * 48 : 0;
    const int jown  = wg * JPW + jlown;
    float hprev = 0.f, xr = 0.f, xz = 0.f, xn = 0.f, bhr = 0.f, bhz = 0.f, bhn = 0.f;
    if (gt >= 0) {
        bhr = bhh[jown]; bhz = bhh[HN + jown]; bhn = bhh[2 * HN + jown];
        const int tok = tokens[(size_t)(R * BPR + bown) * TN + 0];
        const float* g_ = gtab + (size_t)tok * H3N;
        xr = g_[jown]; xz = g_[HN + jown]; xn = g_[2 * HN + jown];
    }

    // depth-1 poll ring prologue: stage (0,0)
    u64 vin = 0;
    if (tid < 384)
        vin = __hip_atomic_load(hb2 + tid, __ATOMIC_RELAXED, __HIP_MEMORY_SCOPE_AGENT);

#pragma unroll 1
    for (int t = 0; t < TN; ++t) {
        const u64 want_pair = ((u64)(unsigned)t << 16) | ((u64)(unsigned)t << 48);
#pragma unroll
        for (int b = 0; b < BPR; ++b) {
            // ---- phase 1: pollers verify (first-try in steady state), deposit,
            //      and immediately issue next stage's poll (stays in flight thru bars)
            if (tid < 384) {
                const u64* cur = hb2 + ((t & 1) * BPR + b) * 384 + tid;
                while ((vin & 0xFFFF0000FFFF0000ull) != want_pair) {
                    __builtin_amdgcn_s_sleep(1);
                    vin = __hip_atomic_load(cur, __ATOMIC_RELAXED, __HIP_MEMORY_SCOPE_AGENT);
                }
                ((unsigned*)hT)[b * 384 + tid] =
                    __builtin_amdgcn_perm((unsigned)(vin >> 32), (unsigned)vin, 0x05040100);
                int b1 = b + 1;
                const int t1 = t + (b1 >> 2);
                b1 &= 3;
                if (t1 < TN)
                    vin = __hip_atomic_load(hb2 + ((t1 & 1) * BPR + b1) * 384 + tid,
                                            __ATOMIC_RELAXED, __HIP_MEMORY_SCOPE_AGENT);
            }
            barrier_lgkm();                    // tile b visible; poll load in flight

            // ---- phase 2: all 12 waves: B-broadcast reads + 18 MFMA + psum writes
            {
                f32x4 acc0 = {0.f, 0.f, 0.f, 0.f};
                f32x4 acc1 = {0.f, 0.f, 0.f, 0.f};
                f32x4 acc2 = {0.f, 0.f, 0.f, 0.f};
#pragma unroll
                for (int ks = 0; ks < 6; ++ks) {
                    // 16-lane broadcast read: every column of B gets the same h
                    f16x8 bf = *(const f16x8*)(hT + b * HN + kbase + ks * 32 + koff8);
                    acc0 = __builtin_amdgcn_mfma_f32_16x16x32_f16(a[0][ks], bf, acc0, 0, 0, 0);
                    acc1 = __builtin_amdgcn_mfma_f32_16x16x32_f16(a[1][ks], bf, acc1, 0, 0, 0);
                    acc2 = __builtin_amdgcn_mfma_f32_16x16x32_f16(a[2][ks], bf, acc2, 0, 0, 0);
                }
                // D layout: col=lane&15 (all equal), row=(lane>>4)*4+reg (m89-verified)
                if ((lane & 15) == 0) {
                    const int r0 = wr * 48 + ((lane >> 4) & 3) * 4;
                    *(f32x4*)&psum[wk][r0]      = acc0;
                    *(f32x4*)&psum[wk][r0 + 16] = acc1;
                    *(f32x4*)&psum[wk][r0 + 32] = acc2;
                }
            }
            barrier_lgkm();                    // psum visible

            // ---- phase 3: gate threads of batch b (overlaps next stage's verify)
            if (gt >= 0 && bown == b) {
                const float sr = (psum[0][jlown]      + psum[1][jlown])
                               + (psum[2][jlown]      + psum[3][jlown]);
                const float sz = (psum[0][48 + jlown] + psum[1][48 + jlown])
                               + (psum[2][48 + jlown] + psum[3][48 + jlown]);
                const float sn = (psum[0][96 + jlown] + psum[1][96 + jlown])
                               + (psum[2][96 + jlown] + psum[3][96 + jlown]);
                const float r  = 1.f / (1.f + __expf(-(xr + sr + bhr)));
                const float z  = 1.f / (1.f + __expf(-(xz + sz + bhz)));
                const float nx = xn + r * (sn + bhn);
                const float n  = 1.f - 2.f / (__expf(2.f * nx) + 1.f);   // tanh
                hprev = (1.f - z) * n + z * hprev;
                unsigned pk = ((unsigned)(t + 1) << 16)
                    | (unsigned)__builtin_bit_cast(unsigned short, (_Float16)hprev);
                const unsigned pk2 = __shfl_down(pk, 1, 64);   // neighbor jlown+1
                if (t < TN - 1) {
                    if (!(jlown & 1))
                        __hip_atomic_store(
                            hb2 + (((t + 1) & 1) * BPR + b) * 384 + wg * 24 + (jlown >> 1),
                            (u64)pk | ((u64)pk2 << 32),
                            __ATOMIC_RELAXED, __HIP_MEMORY_SCOPE_AGENT);
                    // prefetch x-gates for (t+1, bown): consumed a full step later
                    const int tok = tokens[(size_t)(R * BPR + bown) * TN + (t + 1)];
                    const float* g_ = gtab + (size_t)tok * H3N;
                    xr = g_[jown]; xz = g_[HN + jown]; xn = g_[2 * HN + jown];
                } else {
                    hout[(size_t)(R * BPR + bown) * HN + jown] = hprev;
                }
            }
        }
    }
}

// ---------------- K3: logits + log_softmax
__global__ void k_logits(const float* __restrict__ hfin, const float* __restrict__ wout,
                         const float* __restrict__ bout, float* __restrict__ lp) {
    const int b = blockIdx.x;
    const int o = threadIdx.x / 64;
    const int lane = threadIdx.x % 64;
    const float* hrow = hfin + (size_t)b * HN;
    const float* w = wout + (size_t)o * HN;
    float p = 0.f;
    for (int k = lane; k < HN; k += 64) p += hrow[k] * w[k];
    for (int off = 32; off > 0; off >>= 1) p += __shfl_down(p, off, 64);
    __shared__ float lg[ON];
    if (lane == 0) lg[o] = p + bout[o];
    __syncthreads();
    if (threadIdx.x == 0) {
        float m = fmaxf(lg[0], fmaxf(lg[1], lg[2]));
        float s = __expf(lg[0] - m) + __expf(lg[1] - m) + __expf(lg[2] - m);
        float ls = __logf(s);
        lp[b * ON + 0] = lg[0] - m - ls;
        lp[b * ON + 1] = lg[1] - m - ls;
        lp[b * ON + 2] = lg[2] - m - ls;
    }
}

extern "C" void kernel_launch(void* const* d_in, const int* in_sizes, int n_in,
                              void* d_out, int out_size, void* d_ws, size_t ws_size,
                              hipStream_t stream) {
    const int*   tokens = (const int*)d_in[0];
    // d_in[1] = hidden: reference zeroes it, ignored.
    const float* embed  = (const float*)d_in[2];
    const float* wih    = (const float*)d_in[3];
    const float* whh    = (const float*)d_in[4];
    const float* bih    = (const float*)d_in[5];
    const float* bhh    = (const float*)d_in[6];
    const float* wout   = (const float*)d_in[7];
    const float* bout   = (const float*)d_in[8];

    float* out = (float*)d_out;                  // [B*O logprobs][B*H h_final]
    char* ws = (char*)d_ws;
    const size_t GTAB_OFF = 0;                   // 401*2304*4 = 3,695,616
    const size_t HBUF_OFF = 3695616;             // 16*2*4*384*8 = 393,216 (tagged u64)
    float*    gtab = (float*)(ws + GTAB_OFF);
    unsigned* hbuf = (unsigned*)(ws + HBUF_OFF);

    // tag protocol requires tag==0 / h==0 state on EVERY launch (graph-replayed)
    hipMemsetAsync(ws + HBUF_OFF, 0, 393216, stream);

    hipLaunchKernelGGL(k_build_gtab, dim3(H3N / 64, 16), dim3(256), 0, stream,
                       embed, wih, bih, gtab);
    hipLaunchKernelGGL(k_rnn, dim3(NREP * WGPR), dim3(NTH), 0, stream,
                       tokens, whh, gtab, bhh, hbuf, out + BN * ON);
    hipLaunchKernelGGL(k_logits, dim3(BN), dim3(192), 0, stream,
                       out + BN * ON, wout, bout, out);
}